// Round 3
// baseline (179.263 us; speedup 1.0000x reference)
//
#include <hip/hip_runtime.h>

#define NN 32
#define DD 128
#define SS 128
#define MM 64
#define PP 4096              // MM*MM
#define DSZ (DD * SS)

typedef short bf16x8 __attribute__((ext_vector_type(8)));
typedef float f32x4  __attribute__((ext_vector_type(4)));

// Workspace layout (float offsets)
#define OFF_C1T 0                          // c1 transposed bf16 [S][D] (DSZ ushorts)
#define OFF_MC  (OFF_C1T + DSZ / 2)        // column means [N][D][M]
#define OFF_DG  (OFF_MC + NN * DD * MM)    // diagonals    [N][D][M]
#define OFF_MD  (OFF_DG + NN * DD * MM)    // mean(diag)   [N][D]
#define OFF_MA  (OFF_MD + NN * DD)         // mean(all)    [N][D]
#define OFF_UP  (OFF_MA + NN * DD)         // u' [N][S][M] (0.5*(w + v + bias))

__device__ __forceinline__ unsigned int fbits(float f) {
    union { float f; unsigned int u; } c; c.f = f; return c.u;
}

// ---------------------------------------------------------------------------
// Kernel 1: per-(n,d) stats; 4 waves/block, one 64x64 matrix per wave.
// Blocks 0..63 additionally pack c1t bf16 [S][D] from coeffs (1 elem/thread).
// ---------------------------------------------------------------------------
__global__ __launch_bounds__(256) void stats_k(const float* __restrict__ x,
                                               const float* __restrict__ coeffs,
                                               float* __restrict__ mc,
                                               float* __restrict__ dg,
                                               float* __restrict__ md,
                                               float* __restrict__ ma,
                                               unsigned short* __restrict__ c1t) {
    if (blockIdx.x < 64) {
        int g = blockIdx.x * 256 + threadIdx.x;     // g = s*128 + d
        float v = coeffs[(((g & 127) << 7) + (g >> 7)) * 5 + 1];
        unsigned int u = fbits(v);
        u += 0x7fffu + ((u >> 16) & 1);             // round to nearest even
        c1t[g] = (unsigned short)(u >> 16);
    }

    int nd = blockIdx.x * 4 + (threadIdx.x >> 6);
    int l  = threadIdx.x & 63;
    const float* base = x + (size_t)nd * PP;
    int iq = l >> 4, jq = l & 15;

    float4 cs = make_float4(0.f, 0.f, 0.f, 0.f);
    float dv = 0.f;
#pragma unroll
    for (int r = 0; r < 16; ++r) {
        float4 v = *(const float4*)(base + (r * 4 + iq) * MM + jq * 4);
        cs.x += v.x; cs.y += v.y; cs.z += v.z; cs.w += v.w;
        if (r == jq)   // this lane's tile contains diag element i = 4*jq + iq
            dv = (iq == 0) ? v.x : (iq == 1) ? v.y : (iq == 2) ? v.z : v.w;
    }
#pragma unroll
    for (int m = 16; m <= 32; m <<= 1) {
        cs.x += __shfl_xor(cs.x, m);
        cs.y += __shfl_xor(cs.y, m);
        cs.z += __shfl_xor(cs.z, m);
        cs.w += __shfl_xor(cs.w, m);
    }
    if (iq == 0) {
        float4 o = make_float4(cs.x * (1.f / 64.f), cs.y * (1.f / 64.f),
                               cs.z * (1.f / 64.f), cs.w * (1.f / 64.f));
        *(float4*)(mc + nd * MM + jq * 4) = o;
    }
    dg[nd * MM + 4 * jq + iq] = dv;
    float dsum = dv;
#pragma unroll
    for (int m = 1; m <= 32; m <<= 1) dsum += __shfl_xor(dsum, m);
    float tot = cs.x + cs.y + cs.z + cs.w;
#pragma unroll
    for (int m = 1; m <= 8; m <<= 1) tot += __shfl_xor(tot, m);
    if (l == 0) {
        md[nd] = dsum * (1.f / 64.f);
        ma[nd] = tot * (1.f / 4096.f);
    }
}

// ---------------------------------------------------------------------------
// Kernel 1b: u'[n][s][i] = 0.5*( sum_d c0*mc + c2*dg + sum_d c3*md + c4*ma + bias[s] )
// Coeffs read directly from the AoS tensor (lane-broadcast addresses, L2-hot).
// grid (8 sg, N), block 256: i = t&63 (coalesced), 4 s per thread.
// ---------------------------------------------------------------------------
__global__ __launch_bounds__(256) void combine_k(const float* __restrict__ coeffs,
                                                 const float* __restrict__ mc,
                                                 const float* __restrict__ dg,
                                                 const float* __restrict__ md,
                                                 const float* __restrict__ ma,
                                                 const float* __restrict__ bias,
                                                 float* __restrict__ up) {
    int sg = blockIdx.x, n = blockIdx.y;
    int t  = threadIdx.x;
    int i  = t & 63;
    int sq = t >> 6;                 // 0..3 (wave-uniform)
    int s0 = sg * 16 + sq * 4;

    float wacc[4] = {0.f, 0.f, 0.f, 0.f};
    float vacc[4] = {0.f, 0.f, 0.f, 0.f};
#pragma unroll 2
    for (int d = 0; d < DD; ++d) {
        int bidx = (n * DD + d) * MM + i;
        float m   = mc[bidx];
        float g   = dg[bidx];
        float mdv = md[n * DD + d];
        float mav = ma[n * DD + d];
#pragma unroll
        for (int r = 0; r < 4; ++r) {
            const float* cp = coeffs + (size_t)(d * SS + s0 + r) * 5;
            wacc[r] += cp[0] * m + cp[2] * g;
            vacc[r] += cp[3] * mdv + cp[4] * mav;
        }
    }
#pragma unroll
    for (int r = 0; r < 4; ++r) {
        int s = s0 + r;
        up[((size_t)n * SS + s) * MM + i] = 0.5f * (wacc[r] + vacc[r] + bias[s]);
    }
}

// ---------------------------------------------------------------------------
// Kernel 2: MFMA GEMM. out[n,s,p] = sum_d c1[d,s]*x[n,d,p] + u'[s,i] + u'[s,j]
// Block: (p-tile 128, n), 4 waves. Waves are S-MAJOR: each wave covers all
// 128 s x 32 p, so each x element is loaded exactly once per block (A/c1t is
// tiny and L1-hot). B-frags direct from global (8 strided dwords = full cache
// lines), truncate-packed to bf16. One barrier total (u' epilogue stage).
// Nontemporal stores keep out from polluting the LLC (x wants it).
// ---------------------------------------------------------------------------
#define USTR 68   // LDS stride for u' tile [128][64] (+4: 16B-aligned, conflict-free)
__global__ __launch_bounds__(256, 3) void gemm_k(const float* __restrict__ x,
                                                 const unsigned short* __restrict__ c1t,
                                                 const float* __restrict__ up,
                                                 float* __restrict__ out) {
    __shared__ float us[SS * USTR];

    int n  = blockIdx.y;
    int p0 = blockIdx.x * 128;
    int t  = threadIdx.x;
    int w  = t >> 6, l = t & 63;
    int q  = l >> 4, c = l & 15;

    // stage u'[n] (128 s x 64 i fp32) into LDS
    const float* upn = up + (size_t)n * SS * MM;
#pragma unroll
    for (int e = t; e < SS * MM / 4; e += 256) {
        int s  = e >> 4;
        int i4 = (e & 15) * 4;
        *(f32x4*)&us[s * USTR + i4] = *(const f32x4*)(upn + s * MM + i4);
    }
    __syncthreads();

    int p0w = p0 + w * 32;             // this wave's 32-p strip
    int iw  = p0w >> 6;                // wave-uniform i
    const float* xb = x + (size_t)n * DD * PP;

    f32x4 acc[8][2];
#pragma unroll
    for (int a = 0; a < 8; ++a)
#pragma unroll
        for (int b = 0; b < 2; ++b) acc[a][b] = (f32x4)0.f;

#pragma unroll
    for (int kt = 0; kt < 4; ++kt) {
        int k0 = kt * 32 + q * 8;
        bf16x8 af[8];
#pragma unroll
        for (int st = 0; st < 8; ++st)
            af[st] = *(const bf16x8*)(c1t + (size_t)(st * 16 + c) * DD + k0);
#pragma unroll
        for (int pt = 0; pt < 2; ++pt) {
            const float* xp = xb + (size_t)k0 * PP + (p0w + pt * 16 + c);
            float f0 = xp[0 * PP], f1 = xp[1 * PP], f2 = xp[2 * PP], f3 = xp[3 * PP];
            float f4 = xp[4 * PP], f5 = xp[5 * PP], f6 = xp[6 * PP], f7 = xp[7 * PP];
            union { unsigned int u[4]; bf16x8 v; } bb;
            bb.u[0] = __builtin_amdgcn_perm(fbits(f1), fbits(f0), 0x07060302u);
            bb.u[1] = __builtin_amdgcn_perm(fbits(f3), fbits(f2), 0x07060302u);
            bb.u[2] = __builtin_amdgcn_perm(fbits(f5), fbits(f4), 0x07060302u);
            bb.u[3] = __builtin_amdgcn_perm(fbits(f7), fbits(f6), 0x07060302u);
#pragma unroll
            for (int st = 0; st < 8; ++st)
                acc[st][pt] = __builtin_amdgcn_mfma_f32_16x16x32_bf16(af[st], bb.v,
                                                                     acc[st][pt], 0, 0, 0);
        }
    }

    // epilogue: D[row][col]: row = s = st*16 + q*4 + r, col = p-local = c
#pragma unroll
    for (int st = 0; st < 8; ++st) {
#pragma unroll
        for (int r = 0; r < 4; ++r) {
            int s = st * 16 + q * 4 + r;
            float uiv = us[s * USTR + iw];
            float* orow = out + ((size_t)(n * SS + s)) * PP;
#pragma unroll
            for (int pt = 0; pt < 2; ++pt) {
                int p = p0w + pt * 16 + c;
                __builtin_nontemporal_store(acc[st][pt][r] + uiv + us[s * USTR + (p & 63)],
                                            orow + p);
            }
        }
    }
}

// ---------------------------------------------------------------------------
extern "C" void kernel_launch(void* const* d_in, const int* in_sizes, int n_in,
                              void* d_out, int out_size, void* d_ws, size_t ws_size,
                              hipStream_t stream) {
    const float* x      = (const float*)d_in[0];   // [N,D,M,M]
    const float* coeffs = (const float*)d_in[1];   // [D,S,5]
    const float* bias   = (const float*)d_in[2];   // [S]
    float* out = (float*)d_out;
    float* ws  = (float*)d_ws;

    unsigned short* c1t = (unsigned short*)(ws + OFF_C1T);
    float*          mc  = ws + OFF_MC;
    float*          dg  = ws + OFF_DG;
    float*          md  = ws + OFF_MD;
    float*          ma  = ws + OFF_MA;
    float*          up  = ws + OFF_UP;

    stats_k<<<NN * DD / 4, 256, 0, stream>>>(x, coeffs, mc, dg, md, ma, c1t);
    combine_k<<<dim3(8, NN), 256, 0, stream>>>(coeffs, mc, dg, md, ma, bias, up);
    gemm_k<<<dim3(PP / 128, NN), 256, 0, stream>>>(x, c1t, up, out);
}

// Round 4
// 175.991 us; speedup vs baseline: 1.0186x; 1.0186x over previous
//
#include <hip/hip_runtime.h>

#define NN 32
#define DD 128
#define SS 128
#define MM 64
#define PP 4096              // MM*MM
#define DSZ (DD * SS)

typedef short bf16x8 __attribute__((ext_vector_type(8)));
typedef float f32x4  __attribute__((ext_vector_type(4)));

// Workspace layout (float offsets)
#define OFF_C1T 0                          // c1 transposed bf16 [S][D] (DSZ ushorts)
#define OFF_MC  (OFF_C1T + DSZ / 2)        // column means [N][D][M]
#define OFF_DG  (OFF_MC + NN * DD * MM)    // diagonals    [N][D][M]
#define OFF_MD  (OFF_DG + NN * DD * MM)    // mean(diag)   [N][D]
#define OFF_MA  (OFF_MD + NN * DD)         // mean(all)    [N][D]
#define OFF_UP  (OFF_MA + NN * DD)         // u' [N][S][M] (0.5*(w + v + bias))

__device__ __forceinline__ unsigned int fbits(float f) {
    union { float f; unsigned int u; } c; c.f = f; return c.u;
}

// ---------------------------------------------------------------------------
// Kernel 1: per-(n,d) stats; 4 waves/block, one 64x64 matrix per wave.
// Blocks 0..63 additionally pack c1t bf16 [S][D] from coeffs (1 elem/thread).
// ---------------------------------------------------------------------------
__global__ __launch_bounds__(256) void stats_k(const float* __restrict__ x,
                                               const float* __restrict__ coeffs,
                                               float* __restrict__ mc,
                                               float* __restrict__ dg,
                                               float* __restrict__ md,
                                               float* __restrict__ ma,
                                               unsigned short* __restrict__ c1t) {
    if (blockIdx.x < 64) {
        int g = blockIdx.x * 256 + threadIdx.x;     // g = s*128 + d
        float v = coeffs[(((g & 127) << 7) + (g >> 7)) * 5 + 1];
        unsigned int u = fbits(v);
        u += 0x7fffu + ((u >> 16) & 1);             // round to nearest even
        c1t[g] = (unsigned short)(u >> 16);
    }

    int nd = blockIdx.x * 4 + (threadIdx.x >> 6);
    int l  = threadIdx.x & 63;
    const float* base = x + (size_t)nd * PP;
    int iq = l >> 4, jq = l & 15;

    float4 cs = make_float4(0.f, 0.f, 0.f, 0.f);
    float dv = 0.f;
#pragma unroll
    for (int r = 0; r < 16; ++r) {
        float4 v = *(const float4*)(base + (r * 4 + iq) * MM + jq * 4);
        cs.x += v.x; cs.y += v.y; cs.z += v.z; cs.w += v.w;
        if (r == jq)   // this lane's tile contains diag element i = 4*jq + iq
            dv = (iq == 0) ? v.x : (iq == 1) ? v.y : (iq == 2) ? v.z : v.w;
    }
#pragma unroll
    for (int m = 16; m <= 32; m <<= 1) {
        cs.x += __shfl_xor(cs.x, m);
        cs.y += __shfl_xor(cs.y, m);
        cs.z += __shfl_xor(cs.z, m);
        cs.w += __shfl_xor(cs.w, m);
    }
    if (iq == 0) {
        float4 o = make_float4(cs.x * (1.f / 64.f), cs.y * (1.f / 64.f),
                               cs.z * (1.f / 64.f), cs.w * (1.f / 64.f));
        *(float4*)(mc + nd * MM + jq * 4) = o;
    }
    dg[nd * MM + 4 * jq + iq] = dv;
    float dsum = dv;
#pragma unroll
    for (int m = 1; m <= 32; m <<= 1) dsum += __shfl_xor(dsum, m);
    float tot = cs.x + cs.y + cs.z + cs.w;
#pragma unroll
    for (int m = 1; m <= 8; m <<= 1) tot += __shfl_xor(tot, m);
    if (l == 0) {
        md[nd] = dsum * (1.f / 64.f);
        ma[nd] = tot * (1.f / 4096.f);
    }
}

// ---------------------------------------------------------------------------
// Kernel 1b: u'[n][s][i] = 0.5*( sum_d c0*mc + c2*dg + sum_d c3*md + c4*ma + bias[s] )
// ---------------------------------------------------------------------------
__global__ __launch_bounds__(256) void combine_k(const float* __restrict__ coeffs,
                                                 const float* __restrict__ mc,
                                                 const float* __restrict__ dg,
                                                 const float* __restrict__ md,
                                                 const float* __restrict__ ma,
                                                 const float* __restrict__ bias,
                                                 float* __restrict__ up) {
    int sg = blockIdx.x, n = blockIdx.y;
    int t  = threadIdx.x;
    int i  = t & 63;
    int sq = t >> 6;                 // 0..3 (wave-uniform)
    int s0 = sg * 16 + sq * 4;

    float wacc[4] = {0.f, 0.f, 0.f, 0.f};
    float vacc[4] = {0.f, 0.f, 0.f, 0.f};
#pragma unroll 2
    for (int d = 0; d < DD; ++d) {
        int bidx = (n * DD + d) * MM + i;
        float m   = mc[bidx];
        float g   = dg[bidx];
        float mdv = md[n * DD + d];
        float mav = ma[n * DD + d];
#pragma unroll
        for (int r = 0; r < 4; ++r) {
            const float* cp = coeffs + (size_t)(d * SS + s0 + r) * 5;
            wacc[r] += cp[0] * m + cp[2] * g;
            vacc[r] += cp[3] * mdv + cp[4] * mav;
        }
    }
#pragma unroll
    for (int r = 0; r < 4; ++r) {
        int s = s0 + r;
        up[((size_t)n * SS + s) * MM + i] = 0.5f * (wacc[r] + vacc[r] + bias[s]);
    }
}

// ---------------------------------------------------------------------------
// Kernel 2: MFMA GEMM. out[n,s,p] = sum_d c1[d,s]*x[n,d,p] + u'[s,i] + u'[s,j]
// Block: (p-tile 128, n), 4 waves, S-MAJOR (each wave: all 128 s x 32 p, so x
// is read exactly once per block). B-frags direct from global (8 strided
// dwords = full cache lines), truncate-packed to bf16. NO LDS, NO barrier:
// epilogue u' terms read straight from global (n-slice is 32 KB, L2-hot) —
// occupancy capped only by VGPR (~7 blocks/CU vs 3 with the LDS tile), which
// is what a latency-bound direct-load scheme needs. Plain stores: let the
// 256 MiB LLC absorb the 64 MB output (NT stores regressed: in-kernel HBM drain).
// ---------------------------------------------------------------------------
__global__ __launch_bounds__(256) void gemm_k(const float* __restrict__ x,
                                              const unsigned short* __restrict__ c1t,
                                              const float* __restrict__ up,
                                              float* __restrict__ out) {
    int n  = blockIdx.y;
    int p0 = blockIdx.x * 128;
    int t  = threadIdx.x;
    int w  = t >> 6, l = t & 63;
    int q  = l >> 4, c = l & 15;

    int p0w = p0 + w * 32;             // this wave's 32-p strip
    int iw  = p0w >> 6;                // wave-uniform i
    const float* xb  = x + (size_t)n * DD * PP;
    const float* upn = up + (size_t)n * SS * MM;

    f32x4 acc[8][2];
#pragma unroll
    for (int a = 0; a < 8; ++a)
#pragma unroll
        for (int b = 0; b < 2; ++b) acc[a][b] = (f32x4)0.f;

#pragma unroll
    for (int kt = 0; kt < 4; ++kt) {
        int k0 = kt * 32 + q * 8;
        bf16x8 af[8];
#pragma unroll
        for (int st = 0; st < 8; ++st)
            af[st] = *(const bf16x8*)(c1t + (size_t)(st * 16 + c) * DD + k0);
#pragma unroll
        for (int pt = 0; pt < 2; ++pt) {
            const float* xp = xb + (size_t)k0 * PP + (p0w + pt * 16 + c);
            float f0 = xp[0 * PP], f1 = xp[1 * PP], f2 = xp[2 * PP], f3 = xp[3 * PP];
            float f4 = xp[4 * PP], f5 = xp[5 * PP], f6 = xp[6 * PP], f7 = xp[7 * PP];
            union { unsigned int u[4]; bf16x8 v; } bb;
            bb.u[0] = __builtin_amdgcn_perm(fbits(f1), fbits(f0), 0x07060302u);
            bb.u[1] = __builtin_amdgcn_perm(fbits(f3), fbits(f2), 0x07060302u);
            bb.u[2] = __builtin_amdgcn_perm(fbits(f5), fbits(f4), 0x07060302u);
            bb.u[3] = __builtin_amdgcn_perm(fbits(f7), fbits(f6), 0x07060302u);
#pragma unroll
            for (int st = 0; st < 8; ++st)
                acc[st][pt] = __builtin_amdgcn_mfma_f32_16x16x32_bf16(af[st], bb.v,
                                                                     acc[st][pt], 0, 0, 0);
        }
    }

    // epilogue: D[row][col]: row = s = st*16 + q*4 + r, col = p-local = c
    int j0 = p0w & 63;                 // this wave's j base (j = j0 + pt*16 + c)
#pragma unroll
    for (int st = 0; st < 8; ++st) {
#pragma unroll
        for (int r = 0; r < 4; ++r) {
            int s = st * 16 + q * 4 + r;
            const float* uprow = upn + (size_t)s * MM;
            float uiv = uprow[iw];
            float* orow = out + ((size_t)(n * SS + s)) * PP;
#pragma unroll
            for (int pt = 0; pt < 2; ++pt) {
                int jc = j0 + pt * 16 + c;
                orow[p0w + pt * 16 + c] = acc[st][pt][r] + uiv + uprow[jc];
            }
        }
    }
}

// ---------------------------------------------------------------------------
extern "C" void kernel_launch(void* const* d_in, const int* in_sizes, int n_in,
                              void* d_out, int out_size, void* d_ws, size_t ws_size,
                              hipStream_t stream) {
    const float* x      = (const float*)d_in[0];   // [N,D,M,M]
    const float* coeffs = (const float*)d_in[1];   // [D,S,5]
    const float* bias   = (const float*)d_in[2];   // [S]
    float* out = (float*)d_out;
    float* ws  = (float*)d_ws;

    unsigned short* c1t = (unsigned short*)(ws + OFF_C1T);
    float*          mc  = ws + OFF_MC;
    float*          dg  = ws + OFF_DG;
    float*          md  = ws + OFF_MD;
    float*          ma  = ws + OFF_MA;
    float*          up  = ws + OFF_UP;

    stats_k<<<NN * DD / 4, 256, 0, stream>>>(x, coeffs, mc, dg, md, ma, c1t);
    combine_k<<<dim3(8, NN), 256, 0, stream>>>(coeffs, mc, dg, md, ma, bias, up);
    gemm_k<<<dim3(PP / 128, NN), 256, 0, stream>>>(x, c1t, up, out);
}

// Round 5
// 175.439 us; speedup vs baseline: 1.0218x; 1.0031x over previous
//
#include <hip/hip_runtime.h>

#define NN 32
#define DD 128
#define SS 128
#define MM 64
#define PP 4096              // MM*MM
#define DSZ (DD * SS)

typedef short bf16x8 __attribute__((ext_vector_type(8)));
typedef float f32x4  __attribute__((ext_vector_type(4)));

// Workspace layout (float offsets)
#define OFF_C1T 0                          // c1 transposed bf16 [S][D] (DSZ ushorts)
#define OFF_CPL (OFF_C1T + DSZ / 2)        // fp32 planes [4][D][S]: c0,c2,c3,c4
#define OFF_MC  (OFF_CPL + 4 * DSZ)        // column means [N][D][M]
#define OFF_DG  (OFF_MC + NN * DD * MM)    // diagonals    [N][D][M]
#define OFF_MD  (OFF_DG + NN * DD * MM)    // mean(diag)   [N][D]
#define OFF_MA  (OFF_MD + NN * DD)         // mean(all)    [N][D]
#define OFF_UP  (OFF_MA + NN * DD)         // u' [N][M][S]  ([i][s] layout!)

__device__ __forceinline__ unsigned int fbits(float f) {
    union { float f; unsigned int u; } c; c.f = f; return c.u;
}

// ---------------------------------------------------------------------------
// Kernel 1: per-(n,d) stats; 4 waves/block, one 64x64 matrix per wave.
// Blocks 0..63 also pack coeff planes (c0,c2,c3,c4 fp32 [D][S]) + c1t bf16
// [S][D] from the AoS coeffs (1 (d,s) pair per thread; float4+float = whole
// 5-float struct in 2 loads).
// ---------------------------------------------------------------------------
__global__ __launch_bounds__(256) void stats_k(const float* __restrict__ x,
                                               const float* __restrict__ coeffs,
                                               float* __restrict__ mc,
                                               float* __restrict__ dg,
                                               float* __restrict__ md,
                                               float* __restrict__ ma,
                                               float* __restrict__ cpl,
                                               unsigned short* __restrict__ c1t) {
    if (blockIdx.x < 64) {
        int gd = blockIdx.x * 256 + threadIdx.x;    // gd = d*128 + s
        const float* cp = coeffs + (size_t)gd * 5;
        float4 v03 = *(const float4*)cp;
        float  v4  = cp[4];
        cpl[0 * DSZ + gd] = v03.x;                  // c0 plane
        cpl[1 * DSZ + gd] = v03.z;                  // c2 plane
        cpl[2 * DSZ + gd] = v03.w;                  // c3 plane
        cpl[3 * DSZ + gd] = v4;                     // c4 plane
        unsigned int u = fbits(v03.y);
        u += 0x7fffu + ((u >> 16) & 1);             // RNE to bf16
        c1t[(gd & 127) * DD + (gd >> 7)] = (unsigned short)(u >> 16);
    }

    int nd = blockIdx.x * 4 + (threadIdx.x >> 6);
    int l  = threadIdx.x & 63;
    const float* base = x + (size_t)nd * PP;
    int iq = l >> 4, jq = l & 15;

    float4 cs = make_float4(0.f, 0.f, 0.f, 0.f);
    float dv = 0.f;
#pragma unroll
    for (int r = 0; r < 16; ++r) {
        float4 v = *(const float4*)(base + (r * 4 + iq) * MM + jq * 4);
        cs.x += v.x; cs.y += v.y; cs.z += v.z; cs.w += v.w;
        if (r == jq)   // this lane's tile contains diag element i = 4*jq + iq
            dv = (iq == 0) ? v.x : (iq == 1) ? v.y : (iq == 2) ? v.z : v.w;
    }
#pragma unroll
    for (int m = 16; m <= 32; m <<= 1) {
        cs.x += __shfl_xor(cs.x, m);
        cs.y += __shfl_xor(cs.y, m);
        cs.z += __shfl_xor(cs.z, m);
        cs.w += __shfl_xor(cs.w, m);
    }
    if (iq == 0) {
        float4 o = make_float4(cs.x * (1.f / 64.f), cs.y * (1.f / 64.f),
                               cs.z * (1.f / 64.f), cs.w * (1.f / 64.f));
        *(float4*)(mc + nd * MM + jq * 4) = o;
    }
    dg[nd * MM + 4 * jq + iq] = dv;
    float dsum = dv;
#pragma unroll
    for (int m = 1; m <= 32; m <<= 1) dsum += __shfl_xor(dsum, m);
    float tot = cs.x + cs.y + cs.z + cs.w;
#pragma unroll
    for (int m = 1; m <= 8; m <<= 1) tot += __shfl_xor(tot, m);
    if (l == 0) {
        md[nd] = dsum * (1.f / 64.f);
        ma[nd] = tot * (1.f / 4096.f);
    }
}

// ---------------------------------------------------------------------------
// Kernel 1b: u'[n][i][s] = 0.5*( sum_d c0*mc + c2*dg + c3*md + c4*ma + bias[s] )
// Grid (i=64, n=32), block 128: s = tid (lane) -> plane reads are coalesced
// vector loads; mc/dg/md/ma indices are blockIdx+loop only -> wave-uniform,
// compiler emits s_load broadcasts (the R3/R4 combine was 48 µs because these
// derived from threadIdx and became 2048 serialized per-lane flat loads).
// Writes u' [i][s]-major: fully coalesced.
// ---------------------------------------------------------------------------
__global__ __launch_bounds__(128) void combine_k(const float* __restrict__ cpl,
                                                 const float* __restrict__ mc,
                                                 const float* __restrict__ dg,
                                                 const float* __restrict__ md,
                                                 const float* __restrict__ ma,
                                                 const float* __restrict__ bias,
                                                 float* __restrict__ up) {
    int i = blockIdx.x;
    int n = blockIdx.y;
    int s = threadIdx.x;

    const float* c0p = cpl + 0 * DSZ + s;
    const float* c2p = cpl + 1 * DSZ + s;
    const float* c3p = cpl + 2 * DSZ + s;
    const float* c4p = cpl + 3 * DSZ + s;

    float w = 0.f, v = 0.f;
#pragma unroll 4
    for (int d = 0; d < DD; ++d) {
        float mcv = mc[(n * DD + d) * MM + i];   // s_load (wave-uniform)
        float dgv = dg[(n * DD + d) * MM + i];
        float mdv = md[n * DD + d];
        float mav = ma[n * DD + d];
        w += c0p[d * SS] * mcv + c2p[d * SS] * dgv;
        v += c3p[d * SS] * mdv + c4p[d * SS] * mav;
    }
    up[((size_t)n * MM + i) * SS + s] = 0.5f * (w + v + bias[s]);
}

// ---------------------------------------------------------------------------
// Kernel 2: MFMA GEMM — verbatim R2 structure (measured 24 µs; the R3 s-major
// restructure regressed it to 49-51). Block (p-tile 128, n), 4 waves: wave =
// 64 s x 64 p. B-frags direct from global (8 strided dwords = full cache
// lines), truncate-packed bf16. u' tile staged in LDS (odd stride 129 ->
// <=2-way bank conflicts), one barrier total. Plain stores (LLC absorbs).
// ---------------------------------------------------------------------------
#define SSTR 129
__global__ __launch_bounds__(256, 3) void gemm_k(const float* __restrict__ x,
                                                 const unsigned short* __restrict__ c1t,
                                                 const float* __restrict__ up,
                                                 float* __restrict__ out) {
    __shared__ float us[MM * SSTR];   // [i][s], 33 KB

    int n  = blockIdx.y;
    int p0 = blockIdx.x * 128;
    int t  = threadIdx.x;
    int w  = t >> 6, l = t & 63;
    int wp = w & 1, wsn = w >> 1;
    int q  = l >> 4, c = l & 15;

    // stage u'[n] (64 i x 128 s fp32) into LDS
    const float* upn = up + (size_t)n * MM * SS;
#pragma unroll
    for (int e = t; e < MM * SS / 4; e += 256) {
        int i  = e >> 5;
        int s4 = (e & 31) * 4;
        f32x4 vv = *(const f32x4*)(upn + i * SS + s4);
        us[i * SSTR + s4 + 0] = vv.x;
        us[i * SSTR + s4 + 1] = vv.y;
        us[i * SSTR + s4 + 2] = vv.z;
        us[i * SSTR + s4 + 3] = vv.w;
    }
    __syncthreads();

    int p0w = p0 + wp * 64;            // this wave's p base (64-aligned)
    int s0w = wsn * 64;                // this wave's s base
    int iw  = p0w >> 6;                // wave-uniform i
    const float* xb = x + (size_t)n * DD * PP;

    f32x4 acc[4][4];
#pragma unroll
    for (int a = 0; a < 4; ++a)
#pragma unroll
        for (int b = 0; b < 4; ++b) acc[a][b] = (f32x4)0.f;

#pragma unroll
    for (int kt = 0; kt < 4; ++kt) {
        int k0 = kt * 32 + q * 8;
        bf16x8 af[4];
#pragma unroll
        for (int st = 0; st < 4; ++st)
            af[st] = *(const bf16x8*)(c1t + (size_t)(s0w + st * 16 + c) * DD + k0);
#pragma unroll
        for (int pt = 0; pt < 4; ++pt) {
            const float* xp = xb + (size_t)k0 * PP + (p0w + pt * 16 + c);
            float f0 = xp[0 * PP], f1 = xp[1 * PP], f2 = xp[2 * PP], f3 = xp[3 * PP];
            float f4 = xp[4 * PP], f5 = xp[5 * PP], f6 = xp[6 * PP], f7 = xp[7 * PP];
            union { unsigned int u[4]; bf16x8 v; } bb;
            bb.u[0] = __builtin_amdgcn_perm(fbits(f1), fbits(f0), 0x07060302u);
            bb.u[1] = __builtin_amdgcn_perm(fbits(f3), fbits(f2), 0x07060302u);
            bb.u[2] = __builtin_amdgcn_perm(fbits(f5), fbits(f4), 0x07060302u);
            bb.u[3] = __builtin_amdgcn_perm(fbits(f7), fbits(f6), 0x07060302u);
#pragma unroll
            for (int st = 0; st < 4; ++st)
                acc[st][pt] = __builtin_amdgcn_mfma_f32_16x16x32_bf16(af[st], bb.v,
                                                                     acc[st][pt], 0, 0, 0);
        }
    }

    // epilogue: D[row][col]: row = s-local = q*4+reg, col = p-local = c
#pragma unroll
    for (int st = 0; st < 4; ++st) {
#pragma unroll
        for (int r = 0; r < 4; ++r) {
            int s = s0w + st * 16 + q * 4 + r;
            float uiv = us[iw * SSTR + s];
            float* orow = out + ((size_t)(n * SS + s)) * PP;
#pragma unroll
            for (int pt = 0; pt < 4; ++pt) {
                int p = p0w + pt * 16 + c;
                int j = p & 63;
                orow[p] = acc[st][pt][r] + uiv + us[j * SSTR + s];
            }
        }
    }
}

// ---------------------------------------------------------------------------
extern "C" void kernel_launch(void* const* d_in, const int* in_sizes, int n_in,
                              void* d_out, int out_size, void* d_ws, size_t ws_size,
                              hipStream_t stream) {
    const float* x      = (const float*)d_in[0];   // [N,D,M,M]
    const float* coeffs = (const float*)d_in[1];   // [D,S,5]
    const float* bias   = (const float*)d_in[2];   // [S]
    float* out = (float*)d_out;
    float* ws  = (float*)d_ws;

    unsigned short* c1t = (unsigned short*)(ws + OFF_C1T);
    float*          cpl = ws + OFF_CPL;
    float*          mc  = ws + OFF_MC;
    float*          dg  = ws + OFF_DG;
    float*          md  = ws + OFF_MD;
    float*          ma  = ws + OFF_MA;
    float*          up  = ws + OFF_UP;

    stats_k<<<NN * DD / 4, 256, 0, stream>>>(x, coeffs, mc, dg, md, ma, cpl, c1t);
    combine_k<<<dim3(MM, NN), 128, 0, stream>>>(cpl, mc, dg, md, ma, bias, up);
    gemm_k<<<dim3(PP / 128, NN), 256, 0, stream>>>(x, c1t, up, out);
}